// Round 2
// baseline (2931.407 us; speedup 1.0000x reference)
//
#include <hip/hip_runtime.h>
#include <hip/hip_bf16.h>

typedef unsigned short u16;
typedef unsigned int   u32;

typedef __attribute__((ext_vector_type(8))) short short8;
typedef __attribute__((ext_vector_type(4))) float floatx4;

#define HD __device__ __forceinline__

HD float bf16_lo(u32 u) { union { u32 i; float f; } v; v.i = u << 16; return v.f; }
HD float bf16_hi(u32 u) { union { u32 i; float f; } v; v.i = u & 0xffff0000u; return v.f; }
HD u16 f2bf(float f) {
    __hip_bfloat16 h = __float2bfloat16(f);
    u16 s; __builtin_memcpy(&s, &h, 2); return s;
}

// ---- dtype detect: flag=1 if x is packed bf16, 0 if fp32 ----
// Low u16 of each u32: bf16 data -> sane exponent ~always; fp32 data -> low
// mantissa bits are ~uniform, sane ~16% of the time.
__global__ void k_detect(const u32* __restrict__ xw, int* __restrict__ flag) {
    __shared__ int cnt;
    if (threadIdx.x == 0) cnt = 0;
    __syncthreads();
    int sane = 0;
    for (int i = threadIdx.x; i < 4096; i += 256) {
        u32 v = xw[i];
        int e = (v >> 7) & 0xFF;               // exponent field of LOW bf16
        sane += (e >= 107 && e <= 147) ? 1 : 0; // |v| in ~[2^-20, 2^20]
    }
    atomicAdd(&cnt, sane);
    __syncthreads();
    if (threadIdx.x == 0) *flag = (cnt > 2048) ? 1 : 0;
}

// ---- degree: deg[dst] += 1 over real edges ----
__global__ void k_deg(const int* __restrict__ dst, float* __restrict__ deg, int E) {
    int i = blockIdx.x * blockDim.x + threadIdx.x;
    int n = gridDim.x * blockDim.x;
    for (; i < E; i += n) unsafeAtomicAdd(&deg[dst[i]], 1.0f);
}

// ---- dinv[i] = rsqrt(deg[i] + 1)  (self loop), in place ----
__global__ void k_dinv(float* __restrict__ dinv, int N) {
    int i = blockIdx.x * blockDim.x + threadIdx.x;
    if (i < N) dinv[i] = rsqrtf(dinv[i] + 1.0f);
}

// ---- transpose both 128x128 weights -> bf16 Wt[c][k] = W[k][c] ----
__global__ void k_transpose(const void* __restrict__ W1, const void* __restrict__ W2,
                            u16* __restrict__ W1t, u16* __restrict__ W2t,
                            const int* __restrict__ flagp) {
    int isbf = *flagp;
    int i = blockIdx.x * blockDim.x + threadIdx.x;   // 0 .. 32767
    int w = i >> 14;
    int r = (i >> 7) & 127;   // output row  (= W column)
    int c = i & 127;          // output col  (= W row / k)
    const void* W = w ? W2 : W1;
    u16*       Wt = w ? W2t : W1t;
    u16 val;
    if (isbf) val = ((const u16*)W)[c * 128 + r];
    else      val = f2bf(((const float*)W)[c * 128 + r]);
    Wt[r * 128 + c] = val;
}

// ---- GEMM: out[r][c] = sum_k in[r][k] * W[k][c], K=N=128.
// One wave per 16-row tile; 8 col-tiles of 16; mfma_f32_16x16x32_bf16.
// A-frag: lane holds A[m=lane&15][k0 + (lane>>4)*8 + j], j=0..7 (16B contiguous)
// B-frag: lane holds B[k0 + (lane>>4)*8 + j][n=lane&15]  -> contiguous in Wt[n][k]
// D: col = lane&15, row = (lane>>4)*4 + reg   (verified layout, m89/m91)

// Layer 1: input x, dtype per runtime flag (no relu).
__global__ void k_gemm1(const void* __restrict__ inp, const u16* __restrict__ Wt,
                        u16* __restrict__ outb, int ntiles, const int* __restrict__ flagp) {
    int isbf = *flagp;
    int gw   = (blockIdx.x * blockDim.x + threadIdx.x) >> 6;
    int nw   = (gridDim.x * blockDim.x) >> 6;
    int lane = threadIdx.x & 63;
    int m = lane & 15, q = lane >> 4;

    for (int t = gw; t < ntiles; t += nw) {
        long r0 = (long)t * 16;
        floatx4 acc[8];
#pragma unroll
        for (int nt = 0; nt < 8; nt++) acc[nt] = (floatx4)0.0f;

#pragma unroll
        for (int kk = 0; kk < 4; kk++) {
            int k0 = kk * 32 + q * 8;
            short8 a;
            if (isbf) {
                a = *(const short8*)((const u16*)inp + (r0 + m) * 128 + k0);
            } else {
                const float* fp = (const float*)inp + (r0 + m) * 128 + k0;
#pragma unroll
                for (int j = 0; j < 8; j++) a[j] = (short)f2bf(fp[j]);
            }
#pragma unroll
            for (int nt = 0; nt < 8; nt++) {
                short8 b = *(const short8*)(Wt + (nt * 16 + m) * 128 + k0);
                acc[nt] = __builtin_amdgcn_mfma_f32_16x16x32_bf16(a, b, acc[nt], 0, 0, 0);
            }
        }
#pragma unroll
        for (int nt = 0; nt < 8; nt++) {
#pragma unroll
            for (int i = 0; i < 4; i++) {
                long row = r0 + q * 4 + i;
                outb[row * 128 + nt * 16 + m] = f2bf(acc[nt][i]);
            }
        }
    }
}

// Layer 2: input fp32 accumulator, fused relu.
__global__ void k_gemm2(const float* __restrict__ inp, const u16* __restrict__ Wt,
                        u16* __restrict__ outb, int ntiles) {
    int gw   = (blockIdx.x * blockDim.x + threadIdx.x) >> 6;
    int nw   = (gridDim.x * blockDim.x) >> 6;
    int lane = threadIdx.x & 63;
    int m = lane & 15, q = lane >> 4;

    for (int t = gw; t < ntiles; t += nw) {
        long r0 = (long)t * 16;
        floatx4 acc[8];
#pragma unroll
        for (int nt = 0; nt < 8; nt++) acc[nt] = (floatx4)0.0f;

#pragma unroll
        for (int kk = 0; kk < 4; kk++) {
            int k0 = kk * 32 + q * 8;
            short8 a;
            const float* fp = inp + (r0 + m) * 128 + k0;
#pragma unroll
            for (int j = 0; j < 8; j++) a[j] = (short)f2bf(fmaxf(fp[j], 0.0f));
#pragma unroll
            for (int nt = 0; nt < 8; nt++) {
                short8 b = *(const short8*)(Wt + (nt * 16 + m) * 128 + k0);
                acc[nt] = __builtin_amdgcn_mfma_f32_16x16x32_bf16(a, b, acc[nt], 0, 0, 0);
            }
        }
#pragma unroll
        for (int nt = 0; nt < 8; nt++) {
#pragma unroll
            for (int i = 0; i < 4; i++) {
                long row = r0 + q * 4 + i;
                outb[row * 128 + nt * 16 + m] = f2bf(acc[nt][i]);
            }
        }
    }
}

// ---- self-loop init: A[i][:] = H[i][:] * dinv[i]^2  (fp32 out, full overwrite) ----
__global__ void k_selfinit(const u32* __restrict__ Hb2, const float* __restrict__ dinv,
                           float2* __restrict__ A, int total /* N*64 */) {
    int i = blockIdx.x * blockDim.x + threadIdx.x;
    int n = gridDim.x * blockDim.x;
    for (; i < total; i += n) {
        int node = i >> 6;
        float di = dinv[node];
        float c  = di * di;
        u32 h = Hb2[i];
        A[i] = make_float2(bf16_lo(h) * c, bf16_hi(h) * c);
    }
}

// ---- edge aggregation: A[dst][:] += H[src][:] * dinv[src]*dinv[dst] ----
// one wave per edge; lane covers 2 of 128 channels
__global__ void k_edge_agg(const int* __restrict__ ei, const float* __restrict__ dinv,
                           const u16* __restrict__ Hb, float* __restrict__ A, int E) {
    int gw   = (blockIdx.x * blockDim.x + threadIdx.x) >> 6;
    int nw   = (gridDim.x * blockDim.x) >> 6;
    int lane = threadIdx.x & 63;
    const int* srcp = ei;
    const int* dstp = ei + E;
    for (int e = gw; e < E; e += nw) {
        int s = srcp[e], d = dstp[e];
        float coef = dinv[s] * dinv[d];
        u32 h = *(const u32*)(Hb + (size_t)s * 128 + lane * 2);
        float* ap = A + (size_t)d * 128 + lane * 2;
        unsafeAtomicAdd(ap,     bf16_lo(h) * coef);
        unsafeAtomicAdd(ap + 1, bf16_hi(h) * coef);
    }
}

// ---- final convert fp32 -> out dtype per flag ----
__global__ void k_out(const float2* __restrict__ A, void* __restrict__ outp, int total,
                      const int* __restrict__ flagp) {
    int isbf = *flagp;
    int i = blockIdx.x * blockDim.x + threadIdx.x;
    int n = gridDim.x * blockDim.x;
    for (; i < total; i += n) {
        float2 v = A[i];
        if (isbf) ((u32*)outp)[i] = (u32)f2bf(v.x) | ((u32)f2bf(v.y) << 16);
        else      ((float2*)outp)[i] = v;
    }
}

extern "C" void kernel_launch(void* const* d_in, const int* in_sizes, int n_in,
                              void* d_out, int out_size, void* d_ws, size_t ws_size,
                              hipStream_t stream) {
    const void* x  = d_in[0];
    const int*  ei = (const int*)d_in[1];
    const void* W1 = d_in[2];
    const void* W2 = d_in[3];

    const int N = in_sizes[0] / 128;   // 100000
    const int E = in_sizes[1] / 2;     // 1600000

    char* ws = (char*)d_ws;
    // workspace layout
    float* dinv = (float*)ws;                                  // N*4 bytes (deg then dinv)
    int*   flag = (int*)(ws + (448u << 10));                   // 4 bytes
    u16*   W1t  = (u16*)(ws + (512u << 10));                   // 32 KiB
    u16*   W2t  = W1t + 128 * 128;                             // 32 KiB
    u16*   Hb   = (u16*)(ws + (1u << 20));                     // N*128*2 bytes (bf16)
    size_t hbBytes = (size_t)N * 256;
    size_t aOff = (1u << 20) + ((hbBytes + 1023) & ~(size_t)1023);
    float* A    = (float*)(ws + aOff);                         // N*128*4 bytes (fp32)

    k_detect<<<1, 256, 0, stream>>>((const u32*)x, flag);
    hipMemsetAsync(dinv, 0, (size_t)N * 4, stream);
    k_deg<<<1024, 256, 0, stream>>>(ei + E, dinv, E);
    k_dinv<<<(N + 255) / 256, 256, 0, stream>>>(dinv, N);
    k_transpose<<<128, 256, 0, stream>>>(W1, W2, W1t, W2t, flag);

    int ntiles  = N / 16;                 // 6250 (N multiple of 16)
    int gblocks = (ntiles + 3) / 4;       // 4 waves per block

    // layer 1
    k_gemm1<<<gblocks, 256, 0, stream>>>(x, W1t, Hb, ntiles, flag);
    k_selfinit<<<2048, 256, 0, stream>>>((const u32*)Hb, dinv, (float2*)A, N * 64);
    k_edge_agg<<<8192, 256, 0, stream>>>(ei, dinv, Hb, A, E);

    // layer 2 (relu fused into GEMM input read)
    k_gemm2<<<gblocks, 256, 0, stream>>>(A, W2t, Hb, ntiles);
    k_selfinit<<<2048, 256, 0, stream>>>((const u32*)Hb, dinv, (float2*)A, N * 64);
    k_edge_agg<<<8192, 256, 0, stream>>>(ei, dinv, Hb, A, E);

    k_out<<<2048, 256, 0, stream>>>((const float2*)A, (u32*)d_out, N * 64, flag);
}

// Round 3
// 732.907 us; speedup vs baseline: 3.9997x; 3.9997x over previous
//
#include <hip/hip_runtime.h>
#include <hip/hip_bf16.h>

typedef unsigned short u16;
typedef unsigned int   u32;

typedef __attribute__((ext_vector_type(8))) short short8;
typedef __attribute__((ext_vector_type(4))) float floatx4;

#define HD __device__ __forceinline__

HD float bf16_lo(u32 u) { union { u32 i; float f; } v; v.i = u << 16; return v.f; }
HD float bf16_hi(u32 u) { union { u32 i; float f; } v; v.i = u & 0xffff0000u; return v.f; }
HD u16 f2bf(float f) {
    __hip_bfloat16 h = __float2bfloat16(f);
    u16 s; __builtin_memcpy(&s, &h, 2); return s;
}

// ---- dtype detect: flag=1 if x is packed bf16, 0 if fp32 ----
__global__ void k_detect(const u32* __restrict__ xw, int* __restrict__ flag) {
    __shared__ int cnt;
    if (threadIdx.x == 0) cnt = 0;
    __syncthreads();
    int sane = 0;
    for (int i = threadIdx.x; i < 4096; i += 256) {
        u32 v = xw[i];
        int e = (v >> 7) & 0xFF;
        sane += (e >= 107 && e <= 147) ? 1 : 0;
    }
    atomicAdd(&cnt, sane);
    __syncthreads();
    if (threadIdx.x == 0) *flag = (cnt > 2048) ? 1 : 0;
}

// ---- int histogram over dst ----
__global__ void k_hist(const int* __restrict__ dst, int* __restrict__ cnt, int E) {
    int i = blockIdx.x * blockDim.x + threadIdx.x;
    int n = gridDim.x * blockDim.x;
    for (; i < E; i += n) atomicAdd(&cnt[dst[i]], 1);
}

// ---- dinv[i] = rsqrt(cnt[i] + 1) ----
__global__ void k_dinv(const int* __restrict__ cnt, float* __restrict__ dinv, int N) {
    int i = blockIdx.x * blockDim.x + threadIdx.x;
    if (i < N) dinv[i] = rsqrtf((float)cnt[i] + 1.0f);
}

// ---- single-block exclusive scan of cnt[0..N) -> rowptr[0..N], rowptr[N]=E ----
// 1024 threads = 16 waves; tile = 1024 elements; wave shfl scan + LDS combine.
__global__ void k_scan(const int* __restrict__ cnt, int* __restrict__ rowptr, int N) {
    __shared__ int ws[16];
    __shared__ int tile_total;
    int lane = threadIdx.x & 63;
    int wid  = threadIdx.x >> 6;
    int carry = 0;
    int T = (N + 1023) / 1024;
    for (int t = 0; t < T; t++) {
        int i = t * 1024 + threadIdx.x;
        int v = (i < N) ? cnt[i] : 0;
        int x = v;
#pragma unroll
        for (int off = 1; off < 64; off <<= 1) {
            int y = __shfl_up(x, off);
            if (lane >= off) x += y;
        }
        if (lane == 63) ws[wid] = x;
        __syncthreads();
        if (wid == 0) {
            int w = (lane < 16) ? ws[lane] : 0;
            int wx = w;
#pragma unroll
            for (int off = 1; off < 16; off <<= 1) {
                int y = __shfl_up(wx, off);
                if (lane >= off) wx += y;
            }
            if (lane < 16) ws[lane] = wx - w;   // exclusive wave offsets
            if (lane == 15) tile_total = wx;
        }
        __syncthreads();
        int excl = carry + ws[wid] + (x - v);
        if (i < N) rowptr[i] = excl;
        carry += tile_total;
        __syncthreads();
    }
    if (threadIdx.x == 0) rowptr[N] = carry;
}

// ---- cursor init: cursor = rowptr[0..N) ----
__global__ void k_copyint(const int* __restrict__ src, int* __restrict__ dst, int N) {
    int i = blockIdx.x * blockDim.x + threadIdx.x;
    if (i < N) dst[i] = src[i];
}

// ---- scatter: col[cursor[dst]++] = src ----
__global__ void k_scatter(const int* __restrict__ ei, int* __restrict__ cursor,
                          int* __restrict__ col, int E) {
    int i = blockIdx.x * blockDim.x + threadIdx.x;
    int n = gridDim.x * blockDim.x;
    const int* srcp = ei;
    const int* dstp = ei + E;
    for (; i < E; i += n) {
        int pos = atomicAdd(&cursor[dstp[i]], 1);
        col[pos] = srcp[i];
    }
}

// ---- transpose both 128x128 weights -> bf16 Wt[c][k] = W[k][c] ----
__global__ void k_transpose(const void* __restrict__ W1, const void* __restrict__ W2,
                            u16* __restrict__ W1t, u16* __restrict__ W2t,
                            const int* __restrict__ flagp) {
    int isbf = *flagp;
    int i = blockIdx.x * blockDim.x + threadIdx.x;   // 0 .. 32767
    int w = i >> 14;
    int r = (i >> 7) & 127;
    int c = i & 127;
    const void* W = w ? W2 : W1;
    u16*       Wt = w ? W2t : W1t;
    u16 val;
    if (isbf) val = ((const u16*)W)[c * 128 + r];
    else      val = f2bf(((const float*)W)[c * 128 + r]);
    Wt[r * 128 + c] = val;
}

// ---- GEMM layer 1: [N,128]x[128,128], input dtype per flag, bf16 out ----
__global__ void k_gemm1(const void* __restrict__ inp, const u16* __restrict__ Wt,
                        u16* __restrict__ outb, int ntiles, const int* __restrict__ flagp) {
    int isbf = *flagp;
    int gw   = (blockIdx.x * blockDim.x + threadIdx.x) >> 6;
    int nw   = (gridDim.x * blockDim.x) >> 6;
    int lane = threadIdx.x & 63;
    int m = lane & 15, q = lane >> 4;

    for (int t = gw; t < ntiles; t += nw) {
        long r0 = (long)t * 16;
        floatx4 acc[8];
#pragma unroll
        for (int nt = 0; nt < 8; nt++) acc[nt] = (floatx4)0.0f;
#pragma unroll
        for (int kk = 0; kk < 4; kk++) {
            int k0 = kk * 32 + q * 8;
            short8 a;
            if (isbf) {
                a = *(const short8*)((const u16*)inp + (r0 + m) * 128 + k0);
            } else {
                const float* fp = (const float*)inp + (r0 + m) * 128 + k0;
#pragma unroll
                for (int j = 0; j < 8; j++) a[j] = (short)f2bf(fp[j]);
            }
#pragma unroll
            for (int nt = 0; nt < 8; nt++) {
                short8 b = *(const short8*)(Wt + (nt * 16 + m) * 128 + k0);
                acc[nt] = __builtin_amdgcn_mfma_f32_16x16x32_bf16(a, b, acc[nt], 0, 0, 0);
            }
        }
#pragma unroll
        for (int nt = 0; nt < 8; nt++) {
#pragma unroll
            for (int i = 0; i < 4; i++) {
                long row = r0 + q * 4 + i;
                outb[row * 128 + nt * 16 + m] = f2bf(acc[nt][i]);
            }
        }
    }
}

// ---- GEMM layer 2: fp32 input with fused relu, bf16 out ----
__global__ void k_gemm2(const float* __restrict__ inp, const u16* __restrict__ Wt,
                        u16* __restrict__ outb, int ntiles) {
    int gw   = (blockIdx.x * blockDim.x + threadIdx.x) >> 6;
    int nw   = (gridDim.x * blockDim.x) >> 6;
    int lane = threadIdx.x & 63;
    int m = lane & 15, q = lane >> 4;

    for (int t = gw; t < ntiles; t += nw) {
        long r0 = (long)t * 16;
        floatx4 acc[8];
#pragma unroll
        for (int nt = 0; nt < 8; nt++) acc[nt] = (floatx4)0.0f;
#pragma unroll
        for (int kk = 0; kk < 4; kk++) {
            int k0 = kk * 32 + q * 8;
            short8 a;
            const float* fp = inp + (r0 + m) * 128 + k0;
#pragma unroll
            for (int j = 0; j < 8; j++) a[j] = (short)f2bf(fmaxf(fp[j], 0.0f));
#pragma unroll
            for (int nt = 0; nt < 8; nt++) {
                short8 b = *(const short8*)(Wt + (nt * 16 + m) * 128 + k0);
                acc[nt] = __builtin_amdgcn_mfma_f32_16x16x32_bf16(a, b, acc[nt], 0, 0, 0);
            }
        }
#pragma unroll
        for (int nt = 0; nt < 8; nt++) {
#pragma unroll
            for (int i = 0; i < 4; i++) {
                long row = r0 + q * 4 + i;
                outb[row * 128 + nt * 16 + m] = f2bf(acc[nt][i]);
            }
        }
    }
}

// ---- CSR aggregation: one wave per node ----
// A[n][:] = dinv[n]^2 * H[n][:] + sum_{e in in(n)} dinv[col[e]]*dinv[n] * H[col[e]][:]
__global__ void k_csr_agg(const u16* __restrict__ Hb, const int* __restrict__ col,
                          const int* __restrict__ rowptr, const float* __restrict__ dinv,
                          float2* __restrict__ A, int N) {
    int gw   = (blockIdx.x * blockDim.x + threadIdx.x) >> 6;
    int nw   = (gridDim.x * blockDim.x) >> 6;
    int lane = threadIdx.x & 63;
    for (int n = gw; n < N; n += nw) {
        int r0 = rowptr[n], r1 = rowptr[n + 1];
        float di = dinv[n];
        u32 h = *(const u32*)(Hb + (size_t)n * 128 + lane * 2);
        float c = di * di;
        float a0 = bf16_lo(h) * c, a1 = bf16_hi(h) * c;
        int e = r0;
        // unrolled by 2 for load ILP
        for (; e + 1 < r1; e += 2) {
            int s0 = col[e], s1 = col[e + 1];
            float c0 = dinv[s0] * di, c1 = dinv[s1] * di;
            u32 h0 = *(const u32*)(Hb + (size_t)s0 * 128 + lane * 2);
            u32 h1 = *(const u32*)(Hb + (size_t)s1 * 128 + lane * 2);
            a0 += bf16_lo(h0) * c0; a1 += bf16_hi(h0) * c0;
            a0 += bf16_lo(h1) * c1; a1 += bf16_hi(h1) * c1;
        }
        if (e < r1) {
            int s = col[e];
            float cf = dinv[s] * di;
            u32 hh = *(const u32*)(Hb + (size_t)s * 128 + lane * 2);
            a0 += bf16_lo(hh) * cf; a1 += bf16_hi(hh) * cf;
        }
        A[(size_t)n * 64 + lane] = make_float2(a0, a1);
    }
}

// ---- final convert fp32 -> out dtype per flag ----
__global__ void k_out(const float2* __restrict__ A, void* __restrict__ outp, int total,
                      const int* __restrict__ flagp) {
    int isbf = *flagp;
    int i = blockIdx.x * blockDim.x + threadIdx.x;
    int n = gridDim.x * blockDim.x;
    for (; i < total; i += n) {
        float2 v = A[i];
        if (isbf) ((u32*)outp)[i] = (u32)f2bf(v.x) | ((u32)f2bf(v.y) << 16);
        else      ((float2*)outp)[i] = v;
    }
}

extern "C" void kernel_launch(void* const* d_in, const int* in_sizes, int n_in,
                              void* d_out, int out_size, void* d_ws, size_t ws_size,
                              hipStream_t stream) {
    const void* x  = d_in[0];
    const int*  ei = (const int*)d_in[1];
    const void* W1 = d_in[2];
    const void* W2 = d_in[3];

    const int N = in_sizes[0] / 128;   // 100000
    const int E = in_sizes[1] / 2;     // 1600000

    char* ws = (char*)d_ws;
    float* dinv   = (float*)ws;                         // 400KB
    int*   cnt    = (int*)(ws + (512u << 10));          // 400KB (later reused as cursor)
    int*   rowptr = (int*)(ws + (1024u << 10));         // 400KB+4
    int*   flag   = (int*)(ws + (1984u << 10));         // 4B
    u16*   W1t    = (u16*)(ws + (2048u << 10));         // 32KB
    u16*   W2t    = W1t + 128 * 128;                    // 32KB
    int*   col    = (int*)(ws + (3u << 20));            // E*4 = 6.4MB
    u16*   Hb     = (u16*)(ws + (10u << 20));           // N*256B = 25.6MB
    float* A      = (float*)(ws + (40u << 20));         // N*512B = 51.2MB

    // ---- graph preprocessing (CSR by dst) ----
    k_detect<<<1, 256, 0, stream>>>((const u32*)x, flag);
    hipMemsetAsync(cnt, 0, (size_t)N * 4, stream);
    k_hist<<<1024, 256, 0, stream>>>(ei + E, cnt, E);
    k_dinv<<<(N + 255) / 256, 256, 0, stream>>>(cnt, dinv, N);
    k_scan<<<1, 1024, 0, stream>>>(cnt, rowptr, N);
    k_copyint<<<(N + 255) / 256, 256, 0, stream>>>(rowptr, cnt, N);  // cnt becomes cursor
    k_scatter<<<1024, 256, 0, stream>>>(ei, cnt, col, E);
    k_transpose<<<128, 256, 0, stream>>>(W1, W2, W1t, W2t, flag);

    int ntiles  = N / 16;                 // 6250
    int gblocks = (ntiles + 3) / 4;
    int ablocks = (N + 3) / 4;            // one wave per node, 4 waves/block

    // layer 1
    k_gemm1<<<gblocks, 256, 0, stream>>>(x, W1t, Hb, ntiles, flag);
    k_csr_agg<<<ablocks, 256, 0, stream>>>(Hb, col, rowptr, dinv, (float2*)A, N);

    // layer 2 (relu fused into GEMM input read)
    k_gemm2<<<gblocks, 256, 0, stream>>>(A, W2t, Hb, ntiles);
    k_csr_agg<<<ablocks, 256, 0, stream>>>(Hb, col, rowptr, dinv, (float2*)A, N);

    k_out<<<2048, 256, 0, stream>>>((const float2*)A, d_out, N * 64, flag);
}

// Round 4
// 575.968 us; speedup vs baseline: 5.0895x; 1.2725x over previous
//
#include <hip/hip_runtime.h>
#include <hip/hip_bf16.h>

typedef unsigned short u16;
typedef unsigned int   u32;

typedef __attribute__((ext_vector_type(8))) short short8;
typedef __attribute__((ext_vector_type(4))) float floatx4;

#define HD __device__ __forceinline__

HD float bf16_lo(u32 u) { union { u32 i; float f; } v; v.i = u << 16; return v.f; }
HD float bf16_hi(u32 u) { union { u32 i; float f; } v; v.i = u & 0xffff0000u; return v.f; }
HD u16 f2bf(float f) {
    __hip_bfloat16 h = __float2bfloat16(f);
    u16 s; __builtin_memcpy(&s, &h, 2); return s;
}

// ---- dtype detect: flag=1 if x is packed bf16, 0 if fp32 ----
__global__ void k_detect(const u32* __restrict__ xw, int* __restrict__ flag) {
    __shared__ int cnt;
    if (threadIdx.x == 0) cnt = 0;
    __syncthreads();
    int sane = 0;
    for (int i = threadIdx.x; i < 4096; i += 256) {
        u32 v = xw[i];
        int e = (v >> 7) & 0xFF;
        sane += (e >= 107 && e <= 147) ? 1 : 0;
    }
    atomicAdd(&cnt, sane);
    __syncthreads();
    if (threadIdx.x == 0) *flag = (cnt > 2048) ? 1 : 0;
}

// ---- int histogram over dst ----
__global__ void k_hist(const int* __restrict__ dst, int* __restrict__ cnt, int E) {
    int i = blockIdx.x * blockDim.x + threadIdx.x;
    int n = gridDim.x * blockDim.x;
    for (; i < E; i += n) atomicAdd(&cnt[dst[i]], 1);
}

// ---- dinv[i] = rsqrt(cnt[i] + 1) ----
__global__ void k_dinv(const int* __restrict__ cnt, float* __restrict__ dinv, int N) {
    int i = blockIdx.x * blockDim.x + threadIdx.x;
    if (i < N) dinv[i] = rsqrtf((float)cnt[i] + 1.0f);
}

// ---- hierarchical scan: (1) per-1024-block sums ----
__global__ void k_blocksum(const int* __restrict__ cnt, int* __restrict__ partial, int N) {
    __shared__ int wsum[4];
    int base = blockIdx.x * 1024;
    int s = 0;
#pragma unroll
    for (int j = 0; j < 4; j++) {
        int i = base + j * 256 + threadIdx.x;
        if (i < N) s += cnt[i];
    }
#pragma unroll
    for (int off = 32; off > 0; off >>= 1) s += __shfl_down(s, off);
    if ((threadIdx.x & 63) == 0) wsum[threadIdx.x >> 6] = s;
    __syncthreads();
    if (threadIdx.x == 0) partial[blockIdx.x] = wsum[0] + wsum[1] + wsum[2] + wsum[3];
}

// ---- (2) single-wave exclusive scan of P partials; writes rowptr[N]=E ----
__global__ void k_scanpart(int* __restrict__ partial, int* __restrict__ rowptrN, int P) {
    int lane = threadIdx.x;
    int carry = 0;
    int T = (P + 63) / 64;
    for (int t = 0; t < T; t++) {
        int i = t * 64 + lane;
        int v = (i < P) ? partial[i] : 0;
        int x = v;
#pragma unroll
        for (int off = 1; off < 64; off <<= 1) {
            int y = __shfl_up(x, off);
            if (lane >= off) x += y;
        }
        if (i < P) partial[i] = carry + x - v;     // exclusive
        carry += __shfl(x, 63);
    }
    if (lane == 0) *rowptrN = carry;
}

// ---- (3) per-block scan + add partial offset -> rowptr AND cursor ----
__global__ void __launch_bounds__(1024)
k_scanfinal(const int* __restrict__ cnt, const int* __restrict__ partial,
            int* __restrict__ rowptr, int* __restrict__ cursor, int N) {
    __shared__ int ws[16];
    int lane = threadIdx.x & 63, wid = threadIdx.x >> 6;
    int i = blockIdx.x * 1024 + threadIdx.x;
    int v = (i < N) ? cnt[i] : 0;
    int x = v;
#pragma unroll
    for (int off = 1; off < 64; off <<= 1) {
        int y = __shfl_up(x, off);
        if (lane >= off) x += y;
    }
    if (lane == 63) ws[wid] = x;
    __syncthreads();
    if (wid == 0) {
        int w = (lane < 16) ? ws[lane] : 0;
        int wx = w;
#pragma unroll
        for (int off = 1; off < 16; off <<= 1) {
            int y = __shfl_up(wx, off);
            if (lane >= off) wx += y;
        }
        if (lane < 16) ws[lane] = wx - w;
    }
    __syncthreads();
    int excl = partial[blockIdx.x] + ws[wid] + (x - v);
    if (i < N) { rowptr[i] = excl; cursor[i] = excl; }
}

// ---- scatter: col[cursor[dst]++] = src ----
__global__ void k_scatter(const int* __restrict__ ei, int* __restrict__ cursor,
                          int* __restrict__ col, int E) {
    int i = blockIdx.x * blockDim.x + threadIdx.x;
    int n = gridDim.x * blockDim.x;
    const int* srcp = ei;
    const int* dstp = ei + E;
    for (; i < E; i += n) {
        int pos = atomicAdd(&cursor[dstp[i]], 1);
        col[pos] = srcp[i];
    }
}

// ---- transpose both 128x128 weights -> bf16 Wt[c][k] = W[k][c] ----
__global__ void k_transpose(const void* __restrict__ W1, const void* __restrict__ W2,
                            u16* __restrict__ W1t, u16* __restrict__ W2t,
                            const int* __restrict__ flagp) {
    int isbf = *flagp;
    int i = blockIdx.x * blockDim.x + threadIdx.x;   // 0 .. 32767
    int w = i >> 14;
    int r = (i >> 7) & 127;
    int c = i & 127;
    const void* W = w ? W2 : W1;
    u16*       Wt = w ? W2t : W1t;
    u16 val;
    if (isbf) val = ((const u16*)W)[c * 128 + r];
    else      val = f2bf(((const float*)W)[c * 128 + r]);
    Wt[r * 128 + c] = val;
}

// ---- GEMM: out[r][c] = sum_k in[r][k] * W[k][c], K=C=128, bf16 out ----
// One wave per 16-row tile. MODE 0: input x (dtype per flag). MODE 1: fp32 + relu.
// Epilogue stages the 16x128 C-tile in LDS (stride 136 u16) then does
// coalesced short8 stores (1KB per wave-instruction).
template <int MODE>
__global__ void k_gemm(const void* __restrict__ inp, const u16* __restrict__ Wt,
                       u16* __restrict__ outb, int ntiles, const int* __restrict__ flagp) {
    __shared__ u16 stage[4][16 * 136];
    int isbf = (MODE == 0) ? *flagp : 1;
    int gw   = (blockIdx.x * blockDim.x + threadIdx.x) >> 6;
    int nw   = (gridDim.x * blockDim.x) >> 6;
    int lane = threadIdx.x & 63;
    int wid  = threadIdx.x >> 6;
    int m = lane & 15, q = lane >> 4;
    u16* st = stage[wid];

    for (int t = gw; t < ntiles; t += nw) {
        long r0 = (long)t * 16;
        floatx4 acc[8];
#pragma unroll
        for (int nt = 0; nt < 8; nt++) acc[nt] = (floatx4)0.0f;

#pragma unroll
        for (int kk = 0; kk < 4; kk++) {
            int k0 = kk * 32 + q * 8;
            short8 a;
            if (MODE == 1) {
                const float4* fp = (const float4*)((const float*)inp + (r0 + m) * 128 + k0);
                float4 f0 = fp[0], f1 = fp[1];
                a[0] = (short)f2bf(fmaxf(f0.x, 0.0f)); a[1] = (short)f2bf(fmaxf(f0.y, 0.0f));
                a[2] = (short)f2bf(fmaxf(f0.z, 0.0f)); a[3] = (short)f2bf(fmaxf(f0.w, 0.0f));
                a[4] = (short)f2bf(fmaxf(f1.x, 0.0f)); a[5] = (short)f2bf(fmaxf(f1.y, 0.0f));
                a[6] = (short)f2bf(fmaxf(f1.z, 0.0f)); a[7] = (short)f2bf(fmaxf(f1.w, 0.0f));
            } else if (isbf) {
                a = *(const short8*)((const u16*)inp + (r0 + m) * 128 + k0);
            } else {
                const float4* fp = (const float4*)((const float*)inp + (r0 + m) * 128 + k0);
                float4 f0 = fp[0], f1 = fp[1];
                a[0] = (short)f2bf(f0.x); a[1] = (short)f2bf(f0.y);
                a[2] = (short)f2bf(f0.z); a[3] = (short)f2bf(f0.w);
                a[4] = (short)f2bf(f1.x); a[5] = (short)f2bf(f1.y);
                a[6] = (short)f2bf(f1.z); a[7] = (short)f2bf(f1.w);
            }
#pragma unroll
            for (int nt = 0; nt < 8; nt++) {
                short8 b = *(const short8*)(Wt + (nt * 16 + m) * 128 + k0);
                acc[nt] = __builtin_amdgcn_mfma_f32_16x16x32_bf16(a, b, acc[nt], 0, 0, 0);
            }
        }
        // stage C tile to LDS: D layout col=lane&15, row=q*4+i
#pragma unroll
        for (int nt = 0; nt < 8; nt++) {
#pragma unroll
            for (int i = 0; i < 4; i++) {
                st[(q * 4 + i) * 136 + nt * 16 + m] = f2bf(acc[nt][i]);
            }
        }
        __builtin_amdgcn_s_waitcnt(0);   // lgkm drain (same-wave LDS RAW)
        // coalesced store: 4 x (64 lanes x 16B = 1KB)
        u16* gbase = outb + (size_t)r0 * 128;
#pragma unroll
        for (int j = 0; j < 4; j++) {
            int e   = lane * 8 + j * 512;          // u16 index in 16x128 tile
            int row = e >> 7, colu = e & 127;
            short8 vv = *(const short8*)&st[row * 136 + colu];
            *(short8*)(gbase + e) = vv;
        }
    }
}

// ---- CSR aggregation: one wave per node ----
// FINAL=0: write fp32 A.  FINAL=1: write d_out (bf16 or fp32 per flag).
template <int FINAL>
__global__ void k_csr_agg(const u16* __restrict__ Hb, const int* __restrict__ col,
                          const int* __restrict__ rowptr, const float* __restrict__ dinv,
                          void* __restrict__ outp, int N, const int* __restrict__ flagp) {
    int isbf = FINAL ? *flagp : 0;
    int gw   = (blockIdx.x * blockDim.x + threadIdx.x) >> 6;
    int nw   = (gridDim.x * blockDim.x) >> 6;
    int lane = threadIdx.x & 63;
    for (int n = gw; n < N; n += nw) {
        int r0 = rowptr[n], r1 = rowptr[n + 1];
        float di = dinv[n];
        u32 h = *(const u32*)(Hb + (size_t)n * 128 + lane * 2);
        float c = di * di;
        float a0 = bf16_lo(h) * c, a1 = bf16_hi(h) * c;
        int e = r0;
        for (; e + 3 < r1; e += 4) {
            int s0 = col[e], s1 = col[e + 1], s2 = col[e + 2], s3 = col[e + 3];
            float c0 = dinv[s0] * di, c1 = dinv[s1] * di;
            float c2 = dinv[s2] * di, c3 = dinv[s3] * di;
            u32 h0 = *(const u32*)(Hb + (size_t)s0 * 128 + lane * 2);
            u32 h1 = *(const u32*)(Hb + (size_t)s1 * 128 + lane * 2);
            u32 h2 = *(const u32*)(Hb + (size_t)s2 * 128 + lane * 2);
            u32 h3 = *(const u32*)(Hb + (size_t)s3 * 128 + lane * 2);
            a0 += bf16_lo(h0) * c0; a1 += bf16_hi(h0) * c0;
            a0 += bf16_lo(h1) * c1; a1 += bf16_hi(h1) * c1;
            a0 += bf16_lo(h2) * c2; a1 += bf16_hi(h2) * c2;
            a0 += bf16_lo(h3) * c3; a1 += bf16_hi(h3) * c3;
        }
        for (; e < r1; e++) {
            int s = col[e];
            float cf = dinv[s] * di;
            u32 hh = *(const u32*)(Hb + (size_t)s * 128 + lane * 2);
            a0 += bf16_lo(hh) * cf; a1 += bf16_hi(hh) * cf;
        }
        if (FINAL && isbf) {
            ((u32*)outp)[(size_t)n * 64 + lane] = (u32)f2bf(a0) | ((u32)f2bf(a1) << 16);
        } else {
            ((float2*)outp)[(size_t)n * 64 + lane] = make_float2(a0, a1);
        }
    }
}

extern "C" void kernel_launch(void* const* d_in, const int* in_sizes, int n_in,
                              void* d_out, int out_size, void* d_ws, size_t ws_size,
                              hipStream_t stream) {
    const void* x  = d_in[0];
    const int*  ei = (const int*)d_in[1];
    const void* W1 = d_in[2];
    const void* W2 = d_in[3];

    const int N = in_sizes[0] / 128;   // 100000
    const int E = in_sizes[1] / 2;     // 1600000

    char* ws = (char*)d_ws;
    float* dinv    = (float*)ws;                         // 400KB
    int*   cnt     = (int*)(ws + (512u << 10));          // 400KB (reused as cursor)
    int*   rowptr  = (int*)(ws + (1024u << 10));         // 400KB+4
    int*   partial = (int*)(ws + (1536u << 10));         // ~512B
    int*   flag    = (int*)(ws + (1984u << 10));         // 4B
    u16*   W1t     = (u16*)(ws + (2048u << 10));         // 32KB
    u16*   W2t     = W1t + 128 * 128;                    // 32KB
    int*   col     = (int*)(ws + (3u << 20));            // E*4 = 6.4MB
    u16*   Hb      = (u16*)(ws + (10u << 20));           // N*256B = 25.6MB
    float* A       = (float*)(ws + (40u << 20));         // N*512B = 51.2MB

    int P = (N + 1023) / 1024;   // 98 scan blocks

    // ---- graph preprocessing (CSR by dst) ----
    k_detect<<<1, 256, 0, stream>>>((const u32*)x, flag);
    hipMemsetAsync(cnt, 0, (size_t)N * 4, stream);
    k_hist<<<2048, 256, 0, stream>>>(ei + E, cnt, E);
    k_dinv<<<(N + 255) / 256, 256, 0, stream>>>(cnt, dinv, N);
    k_blocksum<<<P, 256, 0, stream>>>(cnt, partial, N);
    k_scanpart<<<1, 64, 0, stream>>>(partial, rowptr + N, P);
    k_scanfinal<<<P, 1024, 0, stream>>>(cnt, partial, rowptr, cnt /*cursor*/, N);
    k_scatter<<<2048, 256, 0, stream>>>(ei, cnt, col, E);
    k_transpose<<<128, 256, 0, stream>>>(W1, W2, W1t, W2t, flag);

    int ntiles  = N / 16;                 // 6250
    int gblocks = (ntiles + 3) / 4;
    int ablocks = (N + 3) / 4;            // one wave per node

    // layer 1
    k_gemm<0><<<gblocks, 256, 0, stream>>>(x, W1t, Hb, ntiles, flag);
    k_csr_agg<0><<<ablocks, 256, 0, stream>>>(Hb, col, rowptr, dinv, A, N, flag);

    // layer 2 (relu fused into GEMM input read; output fused into agg)
    k_gemm<1><<<gblocks, 256, 0, stream>>>(A, W2t, Hb, ntiles, flag);
    k_csr_agg<1><<<ablocks, 256, 0, stream>>>(Hb, col, rowptr, dinv, d_out, N, flag);
}